// Round 8
// baseline (147.399 us; speedup 1.0000x reference)
//
#include <hip/hip_runtime.h>

typedef unsigned int u32;
typedef unsigned long long u64;

#define BN_EPS 1e-3f

// ---------------- workspace layout (bytes) ----------------
// bits1: [256][31][31] u32   conv1->pool->bn1->sign
// w2b  : [9][64]  u32        sign bits of w2 over ic (32)
// w3b  : [9][64]  u64        sign bits of w3 over ic (64)
// d1wb : [144][64] u64       sign bits of d1w rows (bit j = row w*64+j), col oc
// d2wb : [10] u64            sign bits of d2w rows
// t2..t4: per-channel sign thresholds  t = mean - beta*sqrt(var+eps)
static const size_t OFF_BITS1 = 0;            // 984064
static const size_t OFF_W2B   = 1682432;      // 2304
static const size_t OFF_W3B   = 1684736;      // 4608
static const size_t OFF_D1WB  = 1689344;      // 73728
static const size_t OFF_D2WB  = 1763072;      // 128
static const size_t OFF_T2    = 1763328;      // 256
static const size_t OFF_T3    = 1763584;      // 256
static const size_t OFF_T4    = 1763840;      // 256
// total ~1.77 MB

// ---------------- head: conv1 (blocks 0..960) + weight-pack prep (961..1003) --
// conv1: thread = one pooled pixel (b,ph,pw); produces one u32 (32 channels).
// conv1 blocks compute their own t1 thresholds (32 sqrt — free), so prep
// blocks have NO consumer inside this kernel (no inter-block dependency).
__global__ __launch_bounds__(256) void k_head(
    const float* __restrict__ inp, const float* __restrict__ w1,
    const float* __restrict__ m1, const float* __restrict__ v1, const float* __restrict__ be1,
    const float* __restrict__ w2, const float* __restrict__ w3,
    const float* __restrict__ d1w, const float* __restrict__ d2w,
    const float* __restrict__ m2, const float* __restrict__ v2, const float* __restrict__ be2,
    const float* __restrict__ m3, const float* __restrict__ v3, const float* __restrict__ be3,
    const float* __restrict__ m4, const float* __restrict__ v4, const float* __restrict__ be4,
    u32* __restrict__ bits1,
    u32* __restrict__ w2b, u64* __restrict__ w3b, u64* __restrict__ d1wb,
    u64* __restrict__ d2wb, float* __restrict__ t2, float* __restrict__ t3,
    float* __restrict__ t4)
{
    int tid = threadIdx.x;

    if (blockIdx.x >= 961) {             // ---- prep path ----
        int pb = blockIdx.x - 961;
        if (pb < 36) {                   // d1w: 9216 words, [wi][oc]
            int idx = pb * 256 + tid;    // wi = idx>>6, oc = idx&63
            int wi = idx >> 6, oc = idx & 63;
            u64 bits = 0;
            for (int j = 0; j < 64; ++j)
                bits |= (u64)(d1w[(wi * 64 + j) * 64 + oc] >= 0.f) << j;
            d1wb[idx] = bits;
        } else if (pb < 39) {            // w2: 576 words [tap][oc]
            int idx = (pb - 36) * 256 + tid;
            if (idx < 576) {
                int tap = idx >> 6, oc = idx & 63;
                u32 bits = 0;
                for (int ic = 0; ic < 32; ++ic)
                    bits |= (u32)(w2[(tap * 32 + ic) * 64 + oc] >= 0.f) << ic;
                w2b[idx] = bits;
            }
        } else if (pb < 42) {            // w3: 576 words [tap][oc]
            int idx = (pb - 39) * 256 + tid;
            if (idx < 576) {
                int tap = idx >> 6, oc = idx & 63;
                u64 bits = 0;
                for (int ic = 0; ic < 64; ++ic)
                    bits |= (u64)(w3[(tap * 64 + ic) * 64 + oc] >= 0.f) << ic;
                w3b[idx] = bits;
            }
        } else {                         // thresholds + d2w pack
            if (tid < 64)        t2[tid] = m2[tid] - be2[tid] * sqrtf(v2[tid] + BN_EPS);
            else if (tid < 128) { int c = tid - 64;  t3[c] = m3[c] - be3[c] * sqrtf(v3[c] + BN_EPS); }
            else if (tid < 192) { int c = tid - 128; t4[c] = m4[c] - be4[c] * sqrtf(v4[c] + BN_EPS); }
            else if (tid < 202) {
                int oc = tid - 192;      // d2w: [64][10]
                u64 bits = 0;
                for (int j = 0; j < 64; ++j)
                    bits |= (u64)(d2w[j * 10 + oc] >= 0.f) << j;
                d2wb[oc] = bits;
            }
        }
        return;
    }

    // ---- conv1 path ----
    __shared__ float wf[32 * 28];   // [oc][tap], padded 27->28 (float4-aligned rows)
    __shared__ float t1s[32];
    for (int i = tid; i < 864; i += 256) {
        int oc = i / 27, tap = i - oc * 27;
        wf[oc * 28 + tap] = (w1[tap * 32 + oc] >= 0.f) ? 1.f : -1.f;
    }
    if (tid < 32) t1s[tid] = m1[tid] - be1[tid] * sqrtf(v1[tid] + BN_EPS);
    __syncthreads();

    int gid = blockIdx.x * 256 + tid;        // < 246016 = 256*961
    int b = gid / 961;
    int p = gid - b * 961;
    int ph = p / 31, pw = p - ph * 31;

    // 4x4x3 input patch covering the 2x2 conv positions
    float x[4][4][3];
    const float* base = inp + ((b * 64 + 2 * ph) * 64 + 2 * pw) * 3;
#pragma unroll
    for (int i = 0; i < 4; ++i)
#pragma unroll
        for (int j = 0; j < 4; ++j)
#pragma unroll
            for (int k = 0; k < 3; ++k)
                x[i][j][k] = base[(i * 64 + j) * 3 + k];

    u32 word = 0;
#pragma unroll 1
    for (int oc = 0; oc < 32; ++oc) {
        float wv[28];
        const float4* wq = reinterpret_cast<const float4*>(wf + oc * 28);
#pragma unroll
        for (int q = 0; q < 7; ++q) {
            float4 t = wq[q];
            wv[4 * q] = t.x; wv[4 * q + 1] = t.y; wv[4 * q + 2] = t.z; wv[4 * q + 3] = t.w;
        }
        float s00 = 0.f, s01 = 0.f, s10 = 0.f, s11 = 0.f;
#pragma unroll
        for (int ky = 0; ky < 3; ++ky)
#pragma unroll
            for (int kx = 0; kx < 3; ++kx)
#pragma unroll
                for (int ic = 0; ic < 3; ++ic) {
                    float w = wv[(ky * 3 + kx) * 3 + ic];
                    s00 = fmaf(w, x[ky][kx][ic], s00);
                    s01 = fmaf(w, x[ky][kx + 1][ic], s01);
                    s10 = fmaf(w, x[ky + 1][kx][ic], s10);
                    s11 = fmaf(w, x[ky + 1][kx + 1][ic], s11);
                }
        float m = fmaxf(fmaxf(s00, s01), fmaxf(s10, s11));
        if (m >= t1s[oc]) word |= (1u << oc);
    }
    bits1[gid] = word;
}

// ---------------- tail: conv2 + pool + bn2-sign + conv3 + bn3-sign
//                       + dense1 + bn4-sign + dense2 + bn5 + softmax
// one block per image (256 threads = 4 waves). All deps are intra-image:
// conv2 for image b only needs bits1[b], so the whole post-conv1 pipeline
// is block-local. bits1 tile staged in LDS; all per-pixel reads are
// wave-uniform LDS broadcasts (conflict-free fast path).
__global__ __launch_bounds__(256) void k_tail(
    const u32* __restrict__ bits1, const u32* __restrict__ w2b,
    const float* __restrict__ t2,
    const u64* __restrict__ w3b, const float* __restrict__ t3,
    const u64* __restrict__ d1wb, const float* __restrict__ t4,
    const u64* __restrict__ d2wb,
    const float* __restrict__ m5, const float* __restrict__ v5,
    const float* __restrict__ be5, float* __restrict__ out)
{
    __shared__ u32 sb1[961];        // conv1 sign bits for this image [31][31]
    __shared__ u64 sb2[196];        // conv2 output bits [14][14], bit=oc
    __shared__ u64 sb3[144];        // conv3 output bits, word=(h*12+w), bit=ic
    __shared__ int part[4][64];     // dense1 partial popcounts [quarter][oc]

    int tid  = threadIdx.x;
    int lane = tid & 63;
    int wv_  = tid >> 6;            // wave id 0..3
    int b    = blockIdx.x;

    // ---- stage bits1 (3844 B, coalesced) ----
    const u32* src = bits1 + b * 961;
    for (int i = tid; i < 961; i += 256) sb1[i] = src[i];
    __syncthreads();

    // ---- conv2 + pool + bn2-sign: 196 pooled pixels = 4 waves x 49 ----
    {
        u32 w2r[9];
#pragma unroll
        for (int t = 0; t < 9; ++t) w2r[t] = w2b[t * 64 + lane];
        float t2v = t2[lane];

#pragma unroll 1
        for (int i = 0; i < 49; ++i) {
            int p = wv_ * 49 + i;
            int ph = p / 14, pw = p - ph * 14;
            const u32* xb = &sb1[(2 * ph) * 31 + 2 * pw];
            int mn = 1 << 30;
#pragma unroll
            for (int dy = 0; dy < 2; ++dy)
#pragma unroll
                for (int dx = 0; dx < 2; ++dx) {
                    int s = 0;
#pragma unroll
                    for (int ky = 0; ky < 3; ++ky)
#pragma unroll
                        for (int kx = 0; kx < 3; ++kx)
                            s += __popc(xb[(dy + ky) * 31 + dx + kx] ^ w2r[ky * 3 + kx]);
                    mn = min(mn, s);
                }
            u64 word = __ballot((float)(288 - 2 * mn) >= t2v);   // max pool = min popc
            if (lane == 0) sb2[p] = word;
        }
    }
    __syncthreads();

    // ---- conv3 + bn3-sign: 144 positions = 4 waves x 36 ----
    {
        u64 wreg[9];
#pragma unroll
        for (int t = 0; t < 9; ++t) wreg[t] = w3b[t * 64 + lane];
        float t3v = t3[lane];

#pragma unroll 2
        for (int i = 0; i < 36; ++i) {
            int pos = wv_ * 36 + i;
            int h = pos / 12, w = pos - h * 12;
            const u64* xb = &sb2[h * 14 + w];
            int s = 0;
#pragma unroll
            for (int ky = 0; ky < 3; ++ky)
#pragma unroll
                for (int kx = 0; kx < 3; ++kx)
                    s += __popcll(xb[ky * 14 + kx] ^ wreg[ky * 3 + kx]);
            u64 word = __ballot((float)(576 - 2 * s) >= t3v);
            if (lane == 0) sb3[pos] = word;     // word index = h*12+w, bit = ic
        }
    }
    __syncthreads();

    // ---- dense1: thread (q,oc) sums 36 of 144 words ----
    {
        int q = wv_, oc = lane;
        int s = 0;
#pragma unroll 6
        for (int i = 0; i < 36; ++i) {
            int w = q * 36 + i;
            s += __popcll(sb3[w] ^ d1wb[w * 64 + oc]);
        }
        part[q][oc] = s;
    }
    __syncthreads();

    // ---- bn4-sign + dense2 + bn5 + softmax: wave 0 only ----
    if (tid < 64) {
        int s = part[0][tid] + part[1][tid] + part[2][tid] + part[3][tid];
        float val = (float)(9216 - 2 * s);
        u64 xv = __ballot(val >= t4[tid]);   // bit oc of dense1 sign output
        if (tid < 16) {
            int j = tid;
            bool ok = j < 10;
            float y = -1e30f;
            if (ok) {
                int v = 64 - 2 * (int)__popcll(xv ^ d2wb[j]);
                y = ((float)v - m5[j]) * rsqrtf(v5[j] + BN_EPS) + be5[j];
            }
            float mx = y;
#pragma unroll
            for (int off = 8; off >= 1; off >>= 1)
                mx = fmaxf(mx, __shfl_xor(mx, off, 16));
            float e = ok ? expf(y - mx) : 0.f;
            float sum = e;
#pragma unroll
            for (int off = 8; off >= 1; off >>= 1)
                sum += __shfl_xor(sum, off, 16);
            if (ok) out[b * 10 + j] = e / sum;
        }
    }
}

extern "C" void kernel_launch(void* const* d_in, const int* in_sizes, int n_in,
                              void* d_out, int out_size, void* d_ws, size_t ws_size,
                              hipStream_t stream)
{
    const float* inp = (const float*)d_in[0];
    const float* w1  = (const float*)d_in[1];
    const float* w2  = (const float*)d_in[2];
    const float* w3  = (const float*)d_in[3];
    const float* d1w = (const float*)d_in[4];
    const float* d2w = (const float*)d_in[5];
    const float* m1 = (const float*)d_in[6],  *v1 = (const float*)d_in[7],  *be1 = (const float*)d_in[8];
    const float* m2 = (const float*)d_in[9],  *v2 = (const float*)d_in[10], *be2 = (const float*)d_in[11];
    const float* m3 = (const float*)d_in[12], *v3 = (const float*)d_in[13], *be3 = (const float*)d_in[14];
    const float* m4 = (const float*)d_in[15], *v4 = (const float*)d_in[16], *be4 = (const float*)d_in[17];
    const float* m5 = (const float*)d_in[18], *v5 = (const float*)d_in[19], *be5 = (const float*)d_in[20];

    char* ws = (char*)d_ws;
    u32* bits1 = (u32*)(ws + OFF_BITS1);
    u32* w2b   = (u32*)(ws + OFF_W2B);
    u64* w3b   = (u64*)(ws + OFF_W3B);
    u64* d1wb  = (u64*)(ws + OFF_D1WB);
    u64* d2wb  = (u64*)(ws + OFF_D2WB);
    float* t2  = (float*)(ws + OFF_T2);
    float* t3  = (float*)(ws + OFF_T3);
    float* t4  = (float*)(ws + OFF_T4);

    k_head <<<1004, 256, 0, stream>>>(inp, w1, m1, v1, be1,
                                      w2, w3, d1w, d2w,
                                      m2, v2, be2, m3, v3, be3, m4, v4, be4,
                                      bits1, w2b, w3b, d1wb, d2wb, t2, t3, t4);
    k_tail <<<256,  256, 0, stream>>>(bits1, w2b, t2, w3b, t3, d1wb, t4, d2wb,
                                      m5, v5, be5, (float*)d_out);
}

// Round 15
// 139.719 us; speedup vs baseline: 1.0550x; 1.0550x over previous
//
#include <hip/hip_runtime.h>

typedef unsigned int u32;
typedef unsigned long long u64;
typedef float f32x2 __attribute__((ext_vector_type(2)));

#define BN_EPS 1e-3f

// ---------------- workspace layout (bytes) ----------------
// bits1: [256][31][31] u32   conv1->pool->bn1->sign
// w2b  : [9][64]  u32        sign bits of w2 over ic (32)
// w3b  : [9][64]  u64        sign bits of w3 over ic (64)
// d1wb : [144][64] u64       sign bits of d1w rows (bit j = row w*64+j), col oc
// d2wb : [10] u64            sign bits of d2w rows
// t2..t4: per-channel sign thresholds  t = mean - beta*sqrt(var+eps)
static const size_t OFF_BITS1 = 0;            // 984064
static const size_t OFF_W2B   = 1682432;      // 2304
static const size_t OFF_W3B   = 1684736;      // 4608
static const size_t OFF_D1WB  = 1689344;      // 73728
static const size_t OFF_D2WB  = 1763072;      // 128
static const size_t OFF_T2    = 1763328;      // 256
static const size_t OFF_T3    = 1763584;      // 256
static const size_t OFF_T4    = 1763840;      // 256
// total ~1.77 MB

// ---------------- head: conv1 (blocks 0..960) + weight-pack prep (961..1003) --
// conv1: thread = one pooled pixel (b,ph,pw); produces one u32 (32 channels).
// Inner loop packs the 2x2 pool positions into f32x2 accumulators so the
// backend can select v_pk_fma_f32 (fp32 peak on CDNA4 requires packing;
// scalar v_fma_f32 runs at half rate). Per-element op order is identical
// to the scalar version -> bit-exact same results.
__global__ __launch_bounds__(256) void k_head(
    const float* __restrict__ inp, const float* __restrict__ w1,
    const float* __restrict__ m1, const float* __restrict__ v1, const float* __restrict__ be1,
    const float* __restrict__ w2, const float* __restrict__ w3,
    const float* __restrict__ d1w, const float* __restrict__ d2w,
    const float* __restrict__ m2, const float* __restrict__ v2, const float* __restrict__ be2,
    const float* __restrict__ m3, const float* __restrict__ v3, const float* __restrict__ be3,
    const float* __restrict__ m4, const float* __restrict__ v4, const float* __restrict__ be4,
    u32* __restrict__ bits1,
    u32* __restrict__ w2b, u64* __restrict__ w3b, u64* __restrict__ d1wb,
    u64* __restrict__ d2wb, float* __restrict__ t2, float* __restrict__ t3,
    float* __restrict__ t4)
{
    int tid = threadIdx.x;

    if (blockIdx.x >= 961) {             // ---- prep path ----
        int pb = blockIdx.x - 961;
        if (pb < 36) {                   // d1w: 9216 words, [wi][oc]
            int idx = pb * 256 + tid;    // wi = idx>>6, oc = idx&63
            int wi = idx >> 6, oc = idx & 63;
            u64 bits = 0;
            for (int j = 0; j < 64; ++j)
                bits |= (u64)(d1w[(wi * 64 + j) * 64 + oc] >= 0.f) << j;
            d1wb[idx] = bits;
        } else if (pb < 39) {            // w2: 576 words [tap][oc]
            int idx = (pb - 36) * 256 + tid;
            if (idx < 576) {
                int tap = idx >> 6, oc = idx & 63;
                u32 bits = 0;
                for (int ic = 0; ic < 32; ++ic)
                    bits |= (u32)(w2[(tap * 32 + ic) * 64 + oc] >= 0.f) << ic;
                w2b[idx] = bits;
            }
        } else if (pb < 42) {            // w3: 576 words [tap][oc]
            int idx = (pb - 39) * 256 + tid;
            if (idx < 576) {
                int tap = idx >> 6, oc = idx & 63;
                u64 bits = 0;
                for (int ic = 0; ic < 64; ++ic)
                    bits |= (u64)(w3[(tap * 64 + ic) * 64 + oc] >= 0.f) << ic;
                w3b[idx] = bits;
            }
        } else {                         // thresholds + d2w pack
            if (tid < 64)        t2[tid] = m2[tid] - be2[tid] * sqrtf(v2[tid] + BN_EPS);
            else if (tid < 128) { int c = tid - 64;  t3[c] = m3[c] - be3[c] * sqrtf(v3[c] + BN_EPS); }
            else if (tid < 192) { int c = tid - 128; t4[c] = m4[c] - be4[c] * sqrtf(v4[c] + BN_EPS); }
            else if (tid < 202) {
                int oc = tid - 192;      // d2w: [64][10]
                u64 bits = 0;
                for (int j = 0; j < 64; ++j)
                    bits |= (u64)(d2w[j * 10 + oc] >= 0.f) << j;
                d2wb[oc] = bits;
            }
        }
        return;
    }

    // ---- conv1 path ----
    __shared__ float wf[32 * 28];   // [oc][tap], padded 27->28 (float4-aligned rows)
    __shared__ float t1s[32];
    for (int i = tid; i < 864; i += 256) {
        int oc = i / 27, tap = i - oc * 27;
        wf[oc * 28 + tap] = (w1[tap * 32 + oc] >= 0.f) ? 1.f : -1.f;
    }
    if (tid < 32) t1s[tid] = m1[tid] - be1[tid] * sqrtf(v1[tid] + BN_EPS);
    __syncthreads();

    int gid = blockIdx.x * 256 + tid;        // < 246016 = 256*961
    int b = gid / 961;
    int p = gid - b * 961;
    int ph = p / 31, pw = p - ph * 31;

    // 4x4x3 input patch covering the 2x2 conv positions
    float x[4][4][3];
    const float* base = inp + ((b * 64 + 2 * ph) * 64 + 2 * pw) * 3;
#pragma unroll
    for (int i = 0; i < 4; ++i)
#pragma unroll
        for (int j = 0; j < 4; ++j)
#pragma unroll
            for (int k = 0; k < 3; ++k)
                x[i][j][k] = base[(i * 64 + j) * 3 + k];

    u32 word = 0;
#pragma unroll 1
    for (int oc = 0; oc < 32; ++oc) {
        float wv[28];
        const float4* wq = reinterpret_cast<const float4*>(wf + oc * 28);
#pragma unroll
        for (int q = 0; q < 7; ++q) {
            float4 t = wq[q];
            wv[4 * q] = t.x; wv[4 * q + 1] = t.y; wv[4 * q + 2] = t.z; wv[4 * q + 3] = t.w;
        }
        f32x2 a01 = {0.f, 0.f};     // (s00, s01)
        f32x2 a23 = {0.f, 0.f};     // (s10, s11)
#pragma unroll
        for (int ky = 0; ky < 3; ++ky)
#pragma unroll
            for (int kx = 0; kx < 3; ++kx)
#pragma unroll
                for (int ic = 0; ic < 3; ++ic) {
                    float w = wv[(ky * 3 + kx) * 3 + ic];
                    f32x2 ww = {w, w};
                    f32x2 xa = {x[ky][kx][ic],     x[ky][kx + 1][ic]};
                    f32x2 xb = {x[ky + 1][kx][ic], x[ky + 1][kx + 1][ic]};
                    a01 = __builtin_elementwise_fma(ww, xa, a01);
                    a23 = __builtin_elementwise_fma(ww, xb, a23);
                }
        float m = fmaxf(fmaxf(a01.x, a01.y), fmaxf(a23.x, a23.y));
        if (m >= t1s[oc]) word |= (1u << oc);
    }
    bits1[gid] = word;
}

// ---------------- tail: conv2 + pool + bn2-sign + conv3 + bn3-sign
//                       + dense1 + bn4-sign + dense2 + bn5 + softmax
// one block per image, 512 threads = 8 waves (2 waves/SIMD for better
// VALU utilization than the previous 4-wave version). All deps intra-image.
__global__ __launch_bounds__(512) void k_tail(
    const u32* __restrict__ bits1, const u32* __restrict__ w2b,
    const float* __restrict__ t2,
    const u64* __restrict__ w3b, const float* __restrict__ t3,
    const u64* __restrict__ d1wb, const float* __restrict__ t4,
    const u64* __restrict__ d2wb,
    const float* __restrict__ m5, const float* __restrict__ v5,
    const float* __restrict__ be5, float* __restrict__ out)
{
    __shared__ u32 sb1[961];        // conv1 sign bits for this image [31][31]
    __shared__ u64 sb2[196];        // conv2 output bits [14][14], bit=oc
    __shared__ u64 sb3[144];        // conv3 output bits, word=(h*12+w), bit=ic
    __shared__ int part[8][64];     // dense1 partial popcounts [eighth][oc]

    int tid  = threadIdx.x;
    int lane = tid & 63;
    int wv_  = tid >> 6;            // wave id 0..7
    int b    = blockIdx.x;

    // ---- stage bits1 (3844 B, coalesced) ----
    const u32* src = bits1 + b * 961;
    for (int i = tid; i < 961; i += 512) sb1[i] = src[i];
    __syncthreads();

    // ---- conv2 + pool + bn2-sign: 196 pooled pixels round-robin over 8 waves
    {
        u32 w2r[9];
#pragma unroll
        for (int t = 0; t < 9; ++t) w2r[t] = w2b[t * 64 + lane];
        float t2v = t2[lane];

#pragma unroll 1
        for (int p = wv_; p < 196; p += 8) {
            int ph = p / 14, pw = p - ph * 14;
            const u32* xb = &sb1[(2 * ph) * 31 + 2 * pw];
            int mn = 1 << 30;
#pragma unroll
            for (int dy = 0; dy < 2; ++dy)
#pragma unroll
                for (int dx = 0; dx < 2; ++dx) {
                    int s = 0;
#pragma unroll
                    for (int ky = 0; ky < 3; ++ky)
#pragma unroll
                        for (int kx = 0; kx < 3; ++kx)
                            s += __popc(xb[(dy + ky) * 31 + dx + kx] ^ w2r[ky * 3 + kx]);
                    mn = min(mn, s);
                }
            u64 word = __ballot((float)(288 - 2 * mn) >= t2v);   // max pool = min popc
            if (lane == 0) sb2[p] = word;
        }
    }
    __syncthreads();

    // ---- conv3 + bn3-sign: 144 positions round-robin over 8 waves ----
    {
        u64 wreg[9];
#pragma unroll
        for (int t = 0; t < 9; ++t) wreg[t] = w3b[t * 64 + lane];
        float t3v = t3[lane];

#pragma unroll 1
        for (int pos = wv_; pos < 144; pos += 8) {
            int h = pos / 12, w = pos - h * 12;
            const u64* xb = &sb2[h * 14 + w];
            int s = 0;
#pragma unroll
            for (int ky = 0; ky < 3; ++ky)
#pragma unroll
                for (int kx = 0; kx < 3; ++kx)
                    s += __popcll(xb[ky * 14 + kx] ^ wreg[ky * 3 + kx]);
            u64 word = __ballot((float)(576 - 2 * s) >= t3v);
            if (lane == 0) sb3[pos] = word;     // word index = h*12+w, bit = ic
        }
    }
    __syncthreads();

    // ---- dense1: thread (q,oc) sums 18 of 144 words ----
    {
        int q = wv_, oc = lane;
        int s = 0;
#pragma unroll 6
        for (int i = 0; i < 18; ++i) {
            int w = q * 18 + i;
            s += __popcll(sb3[w] ^ d1wb[w * 64 + oc]);
        }
        part[q][oc] = s;
    }
    __syncthreads();

    // ---- bn4-sign + dense2 + bn5 + softmax: wave 0 only ----
    if (tid < 64) {
        int s = 0;
#pragma unroll
        for (int q = 0; q < 8; ++q) s += part[q][tid];
        float val = (float)(9216 - 2 * s);
        u64 xv = __ballot(val >= t4[tid]);   // bit oc of dense1 sign output
        if (tid < 16) {
            int j = tid;
            bool ok = j < 10;
            float y = -1e30f;
            if (ok) {
                int v = 64 - 2 * (int)__popcll(xv ^ d2wb[j]);
                y = ((float)v - m5[j]) * rsqrtf(v5[j] + BN_EPS) + be5[j];
            }
            float mx = y;
#pragma unroll
            for (int off = 8; off >= 1; off >>= 1)
                mx = fmaxf(mx, __shfl_xor(mx, off, 16));
            float e = ok ? expf(y - mx) : 0.f;
            float sum = e;
#pragma unroll
            for (int off = 8; off >= 1; off >>= 1)
                sum += __shfl_xor(sum, off, 16);
            if (ok) out[b * 10 + j] = e / sum;
        }
    }
}

extern "C" void kernel_launch(void* const* d_in, const int* in_sizes, int n_in,
                              void* d_out, int out_size, void* d_ws, size_t ws_size,
                              hipStream_t stream)
{
    const float* inp = (const float*)d_in[0];
    const float* w1  = (const float*)d_in[1];
    const float* w2  = (const float*)d_in[2];
    const float* w3  = (const float*)d_in[3];
    const float* d1w = (const float*)d_in[4];
    const float* d2w = (const float*)d_in[5];
    const float* m1 = (const float*)d_in[6],  *v1 = (const float*)d_in[7],  *be1 = (const float*)d_in[8];
    const float* m2 = (const float*)d_in[9],  *v2 = (const float*)d_in[10], *be2 = (const float*)d_in[11];
    const float* m3 = (const float*)d_in[12], *v3 = (const float*)d_in[13], *be3 = (const float*)d_in[14];
    const float* m4 = (const float*)d_in[15], *v4 = (const float*)d_in[16], *be4 = (const float*)d_in[17];
    const float* m5 = (const float*)d_in[18], *v5 = (const float*)d_in[19], *be5 = (const float*)d_in[20];

    char* ws = (char*)d_ws;
    u32* bits1 = (u32*)(ws + OFF_BITS1);
    u32* w2b   = (u32*)(ws + OFF_W2B);
    u64* w3b   = (u64*)(ws + OFF_W3B);
    u64* d1wb  = (u64*)(ws + OFF_D1WB);
    u64* d2wb  = (u64*)(ws + OFF_D2WB);
    float* t2  = (float*)(ws + OFF_T2);
    float* t3  = (float*)(ws + OFF_T3);
    float* t4  = (float*)(ws + OFF_T4);

    k_head <<<1004, 256, 0, stream>>>(inp, w1, m1, v1, be1,
                                      w2, w3, d1w, d2w,
                                      m2, v2, be2, m3, v3, be3, m4, v4, be4,
                                      bits1, w2b, w3b, d1wb, d2wb, t2, t3, t4);
    k_tail <<<256,  512, 0, stream>>>(bits1, w2b, t2, w3b, t3, d1wb, t4, d2wb,
                                      m5, v5, be5, (float*)d_out);
}